// Round 1
// baseline (1484.021 us; speedup 1.0000x reference)
//
#include <hip/hip_runtime.h>
#include <cstdint>

// RGPR-GNN (GPR-GNN + RGCN basis-decomp convs) for MI355X.
// Strategy: transform-first RGCN. Per layer:
//   Wcat[l] : [K=128, M=1024]  cols 0..127 = root, cols 128+r*128+f = W[r][.,f]
//   GEMM:  cur[N,128] @ Wcat -> curB (root part, fp32, +bias)  and Y (msg part, bf16 [N,896])
//   scatter: curB[dst] += Y[etype][src] * inv_cnt[dst*R+etype]   (float atomics)
//   epilogue: c = (l<2 ? relu : id)(curB); hidden += temp[l+1]*c; curA = c
// Mean aggregation == per-edge scale by 1/cnt(dst,rel), cnt from an int histogram.

constexpr int N_NODES  = 50000;
constexpr int E_EDGES  = 600000;
constexpr int R_REL    = 7;
constexpr int HID      = 128;
constexpr int IN_C     = 256;
constexpr int L_LAYERS = 3;
constexpr int M_CAT    = 1024;   // 128 root + 896 (= 7*128) messages
constexpr int Y_COLS   = 896;

#define DEVI __device__ __forceinline__

DEVI unsigned short f2bf(float f) {
  unsigned u = __float_as_uint(f);
  unsigned r = (u + 0x7FFFu + ((u >> 16) & 1u)) >> 16;  // RNE
  return (unsigned short)r;
}
DEVI float bf2f(unsigned short h) { return __uint_as_float(((unsigned)h) << 16); }

// ---------------------------------------------------------------- build Wcat
__global__ __launch_bounds__(256) void build_wcat(
    const float* __restrict__ comps,   // [L,R,8]
    const float* __restrict__ bases,   // [L,8,128,128]
    const float* __restrict__ roots,   // [L,128,128]
    float* __restrict__ wcat)          // [L,128,1024]
{
  int t = blockIdx.x * 256 + threadIdx.x;
  if (t >= L_LAYERS * 128 * 1024) return;
  int l   = t >> 17;        // /(128*1024)
  int rem = t & 131071;
  int d   = rem >> 10;
  int m   = rem & 1023;
  float v;
  if (m < 128) {
    v = roots[((size_t)l * 128 + d) * 128 + m];
  } else {
    int r = (m - 128) >> 7, f = (m - 128) & 127;
    const float* cp = comps + ((size_t)l * R_REL + r) * 8;
    const float* bp = bases + (((size_t)l * 8) * 128 + d) * 128 + f;
    float s = 0.f;
#pragma unroll
    for (int b = 0; b < 8; ++b) s += cp[b] * bp[(size_t)b * 128 * 128];
    v = s;
  }
  wcat[t] = v;   // layout == l*131072 + d*1024 + m == t
}

// ---------------------------------------------------------------- histogram
__global__ __launch_bounds__(256) void hist_kernel(
    const int* __restrict__ ei, const int* __restrict__ et, int* __restrict__ cnt)
{
  int e = blockIdx.x * 256 + threadIdx.x;
  if (e >= E_EDGES) return;
  int dst = ei[E_EDGES + e];
  atomicAdd(&cnt[dst * R_REL + et[e]], 1);
}

__global__ __launch_bounds__(256) void inv_kernel(float* __restrict__ invc)
{
  int s = blockIdx.x * 256 + threadIdx.x;
  if (s >= N_NODES * R_REL) return;
  int c = ((const int*)invc)[s];
  if (c < 1) c = 1;
  invc[s] = 1.0f / (float)c;
}

// ---------------------------------------------------------------- tiled fp32 GEMM
// BM=BN=128, BK=16, 256 threads, 8x8 microtile.
// EPI 0 (lin1):  out0=hidden, out1=curA, both = temp[0]*(acc + bias[col])
// EPI 1 (layer): blockIdx.y==0 -> out0=curB = acc + bias[col] (fp32)
//                blockIdx.y>0  -> Ybf[row, col-128] = bf16(acc)
template <int KDIM, int EPI>
__global__ __launch_bounds__(256) void gemm_kernel(
    const float* __restrict__ A,
    const float* __restrict__ Bw, int ldb,
    const float* __restrict__ bias,
    const float* __restrict__ temp,
    float* __restrict__ out0,
    float* __restrict__ out1,
    unsigned short* __restrict__ Ybf)
{
  __shared__ float As[16][128];   // [k][m] (transposed store)
  __shared__ float Bs[16][128];   // [k][n]
  const int tid = threadIdx.x;
  const int tx = tid & 15, ty = tid >> 4;
  const int row0 = blockIdx.x * 128;
  const int col0 = blockIdx.y * 128;

  float acc[8][8] = {};

  for (int k0 = 0; k0 < KDIM; k0 += 16) {
    // A tile: 128 rows x 16 cols, 512 float4s, 2 per thread
#pragma unroll
    for (int i = 0; i < 2; ++i) {
      int fid = tid + i * 256;
      int r = fid >> 2, c4 = (fid & 3) << 2;
      int grow = row0 + r;
      float4 v = make_float4(0.f, 0.f, 0.f, 0.f);
      if (grow < N_NODES)
        v = *(const float4*)(A + (size_t)grow * KDIM + k0 + c4);
      As[c4 + 0][r] = v.x; As[c4 + 1][r] = v.y;
      As[c4 + 2][r] = v.z; As[c4 + 3][r] = v.w;
    }
    // B tile: 16 rows x 128 cols
#pragma unroll
    for (int i = 0; i < 2; ++i) {
      int fid = tid + i * 256;
      int r = fid >> 5, c4 = (fid & 31) << 2;
      *(float4*)(&Bs[r][c4]) =
          *(const float4*)(Bw + (size_t)(k0 + r) * ldb + col0 + c4);
    }
    __syncthreads();
#pragma unroll
    for (int kk = 0; kk < 16; ++kk) {
      float a[8], b[8];
      *(float4*)(a)     = *(const float4*)(&As[kk][ty * 8]);
      *(float4*)(a + 4) = *(const float4*)(&As[kk][ty * 8 + 4]);
      *(float4*)(b)     = *(const float4*)(&Bs[kk][tx * 8]);
      *(float4*)(b + 4) = *(const float4*)(&Bs[kk][tx * 8 + 4]);
#pragma unroll
      for (int i = 0; i < 8; ++i)
#pragma unroll
        for (int j = 0; j < 8; ++j) acc[i][j] += a[i] * b[j];
    }
    __syncthreads();
  }

  const int rBase = row0 + ty * 8;
  const int cBase = tx * 8;

  if (EPI == 0) {
    float t0 = temp[0];
    float bb[8];
#pragma unroll
    for (int j = 0; j < 8; ++j) bb[j] = bias[cBase + j];
#pragma unroll
    for (int i = 0; i < 8; ++i) {
      int grow = rBase + i;
      if (grow >= N_NODES) continue;
      float4 v0, v1;
      v0.x = t0 * (acc[i][0] + bb[0]); v0.y = t0 * (acc[i][1] + bb[1]);
      v0.z = t0 * (acc[i][2] + bb[2]); v0.w = t0 * (acc[i][3] + bb[3]);
      v1.x = t0 * (acc[i][4] + bb[4]); v1.y = t0 * (acc[i][5] + bb[5]);
      v1.z = t0 * (acc[i][6] + bb[6]); v1.w = t0 * (acc[i][7] + bb[7]);
      *(float4*)(out0 + (size_t)grow * HID + cBase)     = v0;
      *(float4*)(out0 + (size_t)grow * HID + cBase + 4) = v1;
      *(float4*)(out1 + (size_t)grow * HID + cBase)     = v0;
      *(float4*)(out1 + (size_t)grow * HID + cBase + 4) = v1;
    }
  } else {
    if (blockIdx.y == 0) {
      float bb[8];
#pragma unroll
      for (int j = 0; j < 8; ++j) bb[j] = bias[cBase + j];
#pragma unroll
      for (int i = 0; i < 8; ++i) {
        int grow = rBase + i;
        if (grow >= N_NODES) continue;
        float4 v0, v1;
        v0.x = acc[i][0] + bb[0]; v0.y = acc[i][1] + bb[1];
        v0.z = acc[i][2] + bb[2]; v0.w = acc[i][3] + bb[3];
        v1.x = acc[i][4] + bb[4]; v1.y = acc[i][5] + bb[5];
        v1.z = acc[i][6] + bb[6]; v1.w = acc[i][7] + bb[7];
        *(float4*)(out0 + (size_t)grow * HID + cBase)     = v0;
        *(float4*)(out0 + (size_t)grow * HID + cBase + 4) = v1;
      }
    } else {
      int ycol = col0 - 128 + cBase;   // 0..888
#pragma unroll
      for (int i = 0; i < 8; ++i) {
        int grow = rBase + i;
        if (grow >= N_NODES) continue;
        uint4 p;
        p.x = (unsigned)f2bf(acc[i][0]) | ((unsigned)f2bf(acc[i][1]) << 16);
        p.y = (unsigned)f2bf(acc[i][2]) | ((unsigned)f2bf(acc[i][3]) << 16);
        p.z = (unsigned)f2bf(acc[i][4]) | ((unsigned)f2bf(acc[i][5]) << 16);
        p.w = (unsigned)f2bf(acc[i][6]) | ((unsigned)f2bf(acc[i][7]) << 16);
        *(uint4*)(Ybf + (size_t)grow * Y_COLS + ycol) = p;
      }
    }
  }
}

// ---------------------------------------------------------------- scatter
__global__ __launch_bounds__(256) void scatter_kernel(
    const unsigned short* __restrict__ Y,
    const int* __restrict__ ei, const int* __restrict__ et,
    const float* __restrict__ invc, float* __restrict__ curB)
{
  int t = blockIdx.x * 256 + threadIdx.x;    // E*128 = 76.8M < 2^31
  int e = t >> 7;
  if (e >= E_EDGES) return;
  int d = t & 127;
  int src = ei[e], dst = ei[E_EDGES + e], r = et[e];
  float y = bf2f(Y[(size_t)src * Y_COLS + r * 128 + d]);
  atomicAdd(&curB[(size_t)dst * HID + d], y * invc[dst * R_REL + r]);
}

// ---------------------------------------------------------------- epilogue
__global__ __launch_bounds__(256) void epilogue_kernel(
    const float* __restrict__ curB, float* __restrict__ hidden,
    float* __restrict__ curA, const float* __restrict__ temp, int layer)
{
  int i = blockIdx.x * 256 + threadIdx.x;   // over N*HID/4
  if (i >= N_NODES * HID / 4) return;
  float tl = temp[layer + 1];
  float4 c = ((const float4*)curB)[i];
  if (layer < L_LAYERS - 1) {
    c.x = fmaxf(c.x, 0.f); c.y = fmaxf(c.y, 0.f);
    c.z = fmaxf(c.z, 0.f); c.w = fmaxf(c.w, 0.f);
  }
  float4 h = ((const float4*)hidden)[i];
  h.x += tl * c.x; h.y += tl * c.y; h.z += tl * c.z; h.w += tl * c.w;
  ((float4*)hidden)[i] = h;
  if (layer < L_LAYERS - 1) ((float4*)curA)[i] = c;
}

// ---------------------------------------------------------------- final linear
__global__ __launch_bounds__(256) void final_kernel(
    const float* __restrict__ hidden, const float* __restrict__ w2,
    const float* __restrict__ b2, float* __restrict__ out)
{
  int node = blockIdx.x * 4 + (threadIdx.x >> 6);
  int lane = threadIdx.x & 63;
  if (node >= N_NODES) return;
  float h0 = hidden[(size_t)node * HID + lane];
  float h1 = hidden[(size_t)node * HID + 64 + lane];
  float a0 = h0 * w2[lane * 2 + 0] + h1 * w2[(lane + 64) * 2 + 0];
  float a1 = h0 * w2[lane * 2 + 1] + h1 * w2[(lane + 64) * 2 + 1];
#pragma unroll
  for (int off = 32; off > 0; off >>= 1) {
    a0 += __shfl_down(a0, off);
    a1 += __shfl_down(a1, off);
  }
  if (lane == 0) {
    out[node * 2 + 0] = a0 + b2[0];
    out[node * 2 + 1] = a1 + b2[1];
  }
}

// ---------------------------------------------------------------- launcher
extern "C" void kernel_launch(void* const* d_in, const int* in_sizes, int n_in,
                              void* d_out, int out_size, void* d_ws, size_t ws_size,
                              hipStream_t stream) {
  const float* x     = (const float*)d_in[0];
  const int*   ei    = (const int*)d_in[1];
  const int*   et    = (const int*)d_in[2];
  const float* temp  = (const float*)d_in[3];
  const float* w1    = (const float*)d_in[4];
  const float* b1    = (const float*)d_in[5];
  const float* w2    = (const float*)d_in[6];
  const float* b2    = (const float*)d_in[7];
  const float* comps = (const float*)d_in[8];
  const float* bases = (const float*)d_in[9];
  const float* roots = (const float*)d_in[10];
  const float* cbias = (const float*)d_in[11];

  char* ws = (char*)d_ws;
  size_t off = 0;
  auto take = [&](size_t bytes) {
    char* p = ws + off;
    off = (off + bytes + 255) & ~(size_t)255;
    return p;
  };
  float* wcat   = (float*)take((size_t)L_LAYERS * 128 * 1024 * 4);  // 1.6 MB
  float* invc   = (float*)take((size_t)N_NODES * R_REL * 4);        // 1.4 MB (int cnt -> fp32 inv, in place)
  float* hidden = (float*)take((size_t)N_NODES * HID * 4);          // 25.6 MB
  float* curA   = (float*)take((size_t)N_NODES * HID * 4);          // 25.6 MB
  float* curB   = (float*)take((size_t)N_NODES * HID * 4);          // 25.6 MB
  unsigned short* Ybf = (unsigned short*)take((size_t)N_NODES * Y_COLS * 2); // 89.6 MB

  hipMemsetAsync(invc, 0, (size_t)N_NODES * R_REL * 4, stream);

  hipLaunchKernelGGL(build_wcat, dim3((L_LAYERS * 128 * 1024 + 255) / 256),
                     dim3(256), 0, stream, comps, bases, roots, wcat);
  hipLaunchKernelGGL(hist_kernel, dim3((E_EDGES + 255) / 256), dim3(256), 0,
                     stream, ei, et, (int*)invc);
  hipLaunchKernelGGL(inv_kernel, dim3((N_NODES * R_REL + 255) / 256), dim3(256),
                     0, stream, invc);

  const int rowBlocks = (N_NODES + 127) / 128;   // 391
  // lin1: hidden = curA = temp[0]*(x @ w1 + b1)
  hipLaunchKernelGGL((gemm_kernel<IN_C, 0>), dim3(rowBlocks, 1), dim3(256), 0,
                     stream, x, w1, HID, b1, temp, hidden, curA,
                     (unsigned short*)nullptr);

  for (int l = 0; l < L_LAYERS; ++l) {
    hipLaunchKernelGGL((gemm_kernel<HID, 1>), dim3(rowBlocks, M_CAT / 128),
                       dim3(256), 0, stream, curA, wcat + (size_t)l * 128 * 1024,
                       M_CAT, cbias + (size_t)l * HID, temp, curB, (float*)nullptr,
                       Ybf);
    hipLaunchKernelGGL(scatter_kernel, dim3(E_EDGES * HID / 256), dim3(256), 0,
                       stream, Ybf, ei, et, invc, curB);
    hipLaunchKernelGGL(epilogue_kernel, dim3(N_NODES * HID / 4 / 256), dim3(256),
                       0, stream, curB, hidden, curA, temp, l);
  }

  hipLaunchKernelGGL(final_kernel, dim3((N_NODES + 3) / 4), dim3(256), 0, stream,
                     hidden, w2, b2, (float*)d_out);
}

// Round 3
// 1134.746 us; speedup vs baseline: 1.3078x; 1.3078x over previous
//
#include <hip/hip_runtime.h>
#include <cstdint>

// RGPR-GNN (GPR-GNN + RGCN basis-decomp convs) for MI355X.
// Transform-first RGCN + counting-sort segment aggregation (no atomics in hot path).
// Per layer:
//   GEMM:  cur[N,128] @ Wcat[128,1024] -> curB (root+bias, fp32) and Y (messages, bf16 [N,896])
//   aggregate: one block owns dst; acc = sum_e Y[rel_e][src_e]*inv_cnt(dst,rel_e); curB[dst]+=acc
//   epilogue: c = (l<2 ? relu : id)(curB); hidden += temp[l+1]*c; curA = c
// Edge sort (by dst) runs ONCE per call: hist -> 3-kernel exclusive scan -> placement.

constexpr int N_NODES  = 50000;
constexpr int E_EDGES  = 600000;
constexpr int R_REL    = 7;
constexpr int HID      = 128;
constexpr int IN_C     = 256;
constexpr int L_LAYERS = 3;
constexpr int M_CAT    = 1024;   // 128 root + 896 (= 7*128) messages
constexpr int Y_COLS   = 896;
constexpr int SCAN_BLOCKS = (N_NODES + 255) / 256;   // 196

#define DEVI __device__ __forceinline__

DEVI unsigned short f2bf(float f) {
  unsigned u = __float_as_uint(f);
  unsigned r = (u + 0x7FFFu + ((u >> 16) & 1u)) >> 16;  // RNE
  return (unsigned short)r;
}
DEVI float bf2f(unsigned short h) { return __uint_as_float(((unsigned)h) << 16); }

// ---------------------------------------------------------------- build Wcat
__global__ __launch_bounds__(256) void build_wcat(
    const float* __restrict__ comps,   // [L,R,8]
    const float* __restrict__ bases,   // [L,8,128,128]
    const float* __restrict__ roots,   // [L,128,128]
    float* __restrict__ wcat)          // [L,128,1024]
{
  int t = blockIdx.x * 256 + threadIdx.x;
  if (t >= L_LAYERS * 128 * 1024) return;
  int l   = t >> 17;
  int rem = t & 131071;
  int d   = rem >> 10;
  int m   = rem & 1023;
  float v;
  if (m < 128) {
    v = roots[((size_t)l * 128 + d) * 128 + m];
  } else {
    int r = (m - 128) >> 7, f = (m - 128) & 127;
    const float* cp = comps + ((size_t)l * R_REL + r) * 8;
    const float* bp = bases + (((size_t)l * 8) * 128 + d) * 128 + f;
    float s = 0.f;
#pragma unroll
    for (int b = 0; b < 8; ++b) s += cp[b] * bp[(size_t)b * 128 * 128];
    v = s;
  }
  wcat[t] = v;
}

// ---------------------------------------------------------------- histograms
__global__ __launch_bounds__(256) void hist_kernel(
    const int* __restrict__ ei, const int* __restrict__ et,
    int* __restrict__ cntRel, int* __restrict__ cntDst)
{
  int e = blockIdx.x * 256 + threadIdx.x;
  if (e >= E_EDGES) return;
  int dst = ei[E_EDGES + e];
  atomicAdd(&cntRel[dst * R_REL + et[e]], 1);
  atomicAdd(&cntDst[dst], 1);
}

__global__ __launch_bounds__(256) void inv_kernel(float* __restrict__ invc)
{
  int s = blockIdx.x * 256 + threadIdx.x;
  if (s >= N_NODES * R_REL) return;
  int c = ((const int*)invc)[s];
  if (c < 1) c = 1;
  invc[s] = 1.0f / (float)c;
}

// ---------------------------------------------------------------- scan (3-kernel)
__global__ __launch_bounds__(256) void scan1_kernel(
    const int* __restrict__ cntDst, int* __restrict__ tmpOff,
    int* __restrict__ blockSums)
{
  __shared__ int s[256];
  int i = blockIdx.x * 256 + threadIdx.x;
  int v = (i < N_NODES) ? cntDst[i] : 0;
  s[threadIdx.x] = v;
  __syncthreads();
#pragma unroll
  for (int d = 1; d < 256; d <<= 1) {
    int t = (threadIdx.x >= d) ? s[threadIdx.x - d] : 0;
    __syncthreads();
    s[threadIdx.x] += t;
    __syncthreads();
  }
  if (i < N_NODES) tmpOff[i] = s[threadIdx.x] - v;   // exclusive within block
  if (threadIdx.x == 255) blockSums[blockIdx.x] = s[255];
}

__global__ __launch_bounds__(256) void scan2_kernel(int* __restrict__ blockSums)
{
  __shared__ int s[256];
  int v = (threadIdx.x < SCAN_BLOCKS) ? blockSums[threadIdx.x] : 0;
  s[threadIdx.x] = v;
  __syncthreads();
#pragma unroll
  for (int d = 1; d < 256; d <<= 1) {
    int t = (threadIdx.x >= d) ? s[threadIdx.x - d] : 0;
    __syncthreads();
    s[threadIdx.x] += t;
    __syncthreads();
  }
  if (threadIdx.x < SCAN_BLOCKS) blockSums[threadIdx.x] = s[threadIdx.x] - v;
}

__global__ __launch_bounds__(256) void scan3_kernel(
    const int* __restrict__ tmpOff, const int* __restrict__ blockSums,
    int* __restrict__ dstStart)
{
  int i = blockIdx.x * 256 + threadIdx.x;
  if (i < N_NODES) dstStart[i] = tmpOff[i] + blockSums[blockIdx.x];
  if (i == 0) dstStart[N_NODES] = E_EDGES;
}

// ---------------------------------------------------------------- placement
__global__ __launch_bounds__(256) void place_kernel(
    const int* __restrict__ ei, const int* __restrict__ et,
    const int* __restrict__ dstStart, int* __restrict__ cursor,
    int* __restrict__ epack)
{
  int e = blockIdx.x * 256 + threadIdx.x;
  if (e >= E_EDGES) return;
  int src = ei[e], dst = ei[E_EDGES + e], r = et[e];
  int pos = dstStart[dst] + atomicAdd(&cursor[dst], 1);
  epack[pos] = src | (r << 16);   // src < 65536, r < 8
}

// ---------------------------------------------------------------- tiled fp32 GEMM
template <int KDIM, int EPI>
__global__ __launch_bounds__(256) void gemm_kernel(
    const float* __restrict__ A,
    const float* __restrict__ Bw, int ldb,
    const float* __restrict__ bias,
    const float* __restrict__ temp,
    float* __restrict__ out0,
    float* __restrict__ out1,
    unsigned short* __restrict__ Ybf)
{
  __shared__ float As[16][128];
  __shared__ float Bs[16][128];
  const int tid = threadIdx.x;
  const int tx = tid & 15, ty = tid >> 4;
  const int row0 = blockIdx.x * 128;
  const int col0 = blockIdx.y * 128;

  float acc[8][8] = {};

  for (int k0 = 0; k0 < KDIM; k0 += 16) {
#pragma unroll
    for (int i = 0; i < 2; ++i) {
      int fid = tid + i * 256;
      int r = fid >> 2, c4 = (fid & 3) << 2;
      int grow = row0 + r;
      float4 v = make_float4(0.f, 0.f, 0.f, 0.f);
      if (grow < N_NODES)
        v = *(const float4*)(A + (size_t)grow * KDIM + k0 + c4);
      As[c4 + 0][r] = v.x; As[c4 + 1][r] = v.y;
      As[c4 + 2][r] = v.z; As[c4 + 3][r] = v.w;
    }
#pragma unroll
    for (int i = 0; i < 2; ++i) {
      int fid = tid + i * 256;
      int r = fid >> 5, c4 = (fid & 31) << 2;
      *(float4*)(&Bs[r][c4]) =
          *(const float4*)(Bw + (size_t)(k0 + r) * ldb + col0 + c4);
    }
    __syncthreads();
#pragma unroll
    for (int kk = 0; kk < 16; ++kk) {
      float a[8], b[8];
      *(float4*)(a)     = *(const float4*)(&As[kk][ty * 8]);
      *(float4*)(a + 4) = *(const float4*)(&As[kk][ty * 8 + 4]);
      *(float4*)(b)     = *(const float4*)(&Bs[kk][tx * 8]);
      *(float4*)(b + 4) = *(const float4*)(&Bs[kk][tx * 8 + 4]);
#pragma unroll
      for (int i = 0; i < 8; ++i)
#pragma unroll
        for (int j = 0; j < 8; ++j) acc[i][j] += a[i] * b[j];
    }
    __syncthreads();
  }

  const int rBase = row0 + ty * 8;
  const int cBase = tx * 8;

  if (EPI == 0) {
    float t0 = temp[0];
    float bb[8];
#pragma unroll
    for (int j = 0; j < 8; ++j) bb[j] = bias[cBase + j];
#pragma unroll
    for (int i = 0; i < 8; ++i) {
      int grow = rBase + i;
      if (grow >= N_NODES) continue;
      float4 v0, v1;
      v0.x = t0 * (acc[i][0] + bb[0]); v0.y = t0 * (acc[i][1] + bb[1]);
      v0.z = t0 * (acc[i][2] + bb[2]); v0.w = t0 * (acc[i][3] + bb[3]);
      v1.x = t0 * (acc[i][4] + bb[4]); v1.y = t0 * (acc[i][5] + bb[5]);
      v1.z = t0 * (acc[i][6] + bb[6]); v1.w = t0 * (acc[i][7] + bb[7]);
      *(float4*)(out0 + (size_t)grow * HID + cBase)     = v0;
      *(float4*)(out0 + (size_t)grow * HID + cBase + 4) = v1;
      *(float4*)(out1 + (size_t)grow * HID + cBase)     = v0;
      *(float4*)(out1 + (size_t)grow * HID + cBase + 4) = v1;
    }
  } else {
    if (blockIdx.y == 0) {
      float bb[8];
#pragma unroll
      for (int j = 0; j < 8; ++j) bb[j] = bias[cBase + j];
#pragma unroll
      for (int i = 0; i < 8; ++i) {
        int grow = rBase + i;
        if (grow >= N_NODES) continue;
        float4 v0, v1;
        v0.x = acc[i][0] + bb[0]; v0.y = acc[i][1] + bb[1];
        v0.z = acc[i][2] + bb[2]; v0.w = acc[i][3] + bb[3];
        v1.x = acc[i][4] + bb[4]; v1.y = acc[i][5] + bb[5];
        v1.z = acc[i][6] + bb[6]; v1.w = acc[i][7] + bb[7];
        *(float4*)(out0 + (size_t)grow * HID + cBase)     = v0;
        *(float4*)(out0 + (size_t)grow * HID + cBase + 4) = v1;
      }
    } else {
      int ycol = col0 - 128 + cBase;
#pragma unroll
      for (int i = 0; i < 8; ++i) {
        int grow = rBase + i;
        if (grow >= N_NODES) continue;
        uint4 p;
        p.x = (unsigned)f2bf(acc[i][0]) | ((unsigned)f2bf(acc[i][1]) << 16);
        p.y = (unsigned)f2bf(acc[i][2]) | ((unsigned)f2bf(acc[i][3]) << 16);
        p.z = (unsigned)f2bf(acc[i][4]) | ((unsigned)f2bf(acc[i][5]) << 16);
        p.w = (unsigned)f2bf(acc[i][6]) | ((unsigned)f2bf(acc[i][7]) << 16);
        *(uint4*)(Ybf + (size_t)grow * Y_COLS + ycol) = p;
      }
    }
  }
}

// ---------------------------------------------------------------- segment aggregate
// Block = 256 threads = 2 dsts x 128 dims. One block owns its dsts: no atomics.
__global__ __launch_bounds__(256) void aggregate_kernel(
    const unsigned short* __restrict__ Y,
    const int* __restrict__ epack,
    const int* __restrict__ dstStart,
    const float* __restrict__ invc,
    float* __restrict__ curB)
{
  int dst = blockIdx.x * 2 + (threadIdx.x >> 7);
  if (dst >= N_NODES) return;
  int d = threadIdx.x & 127;
  int p0 = dstStart[dst], p1 = dstStart[dst + 1];
  float acc = 0.f;
  for (int p = p0; p < p1; ++p) {
    int pk = epack[p];
    int src = pk & 0xFFFF;
    int r   = pk >> 16;
    acc += bf2f(Y[(size_t)src * Y_COLS + r * 128 + d]) * invc[dst * R_REL + r];
  }
  curB[(size_t)dst * HID + d] += acc;
}

// ---------------------------------------------------------------- epilogue
__global__ __launch_bounds__(256) void epilogue_kernel(
    const float* __restrict__ curB, float* __restrict__ hidden,
    float* __restrict__ curA, const float* __restrict__ temp, int layer)
{
  int i = blockIdx.x * 256 + threadIdx.x;
  if (i >= N_NODES * HID / 4) return;
  float tl = temp[layer + 1];
  float4 c = ((const float4*)curB)[i];
  if (layer < L_LAYERS - 1) {
    c.x = fmaxf(c.x, 0.f); c.y = fmaxf(c.y, 0.f);
    c.z = fmaxf(c.z, 0.f); c.w = fmaxf(c.w, 0.f);
  }
  float4 h = ((const float4*)hidden)[i];
  h.x += tl * c.x; h.y += tl * c.y; h.z += tl * c.z; h.w += tl * c.w;
  ((float4*)hidden)[i] = h;
  if (layer < L_LAYERS - 1) ((float4*)curA)[i] = c;
}

// ---------------------------------------------------------------- final linear
__global__ __launch_bounds__(256) void final_kernel(
    const float* __restrict__ hidden, const float* __restrict__ w2,
    const float* __restrict__ b2, float* __restrict__ out)
{
  int node = blockIdx.x * 4 + (threadIdx.x >> 6);
  int lane = threadIdx.x & 63;
  if (node >= N_NODES) return;
  float h0 = hidden[(size_t)node * HID + lane];
  float h1 = hidden[(size_t)node * HID + 64 + lane];
  float a0 = h0 * w2[lane * 2 + 0] + h1 * w2[(lane + 64) * 2 + 0];
  float a1 = h0 * w2[lane * 2 + 1] + h1 * w2[(lane + 64) * 2 + 1];
#pragma unroll
  for (int off = 32; off > 0; off >>= 1) {
    a0 += __shfl_down(a0, off);
    a1 += __shfl_down(a1, off);
  }
  if (lane == 0) {
    out[node * 2 + 0] = a0 + b2[0];
    out[node * 2 + 1] = a1 + b2[1];
  }
}

// ---------------------------------------------------------------- launcher
extern "C" void kernel_launch(void* const* d_in, const int* in_sizes, int n_in,
                              void* d_out, int out_size, void* d_ws, size_t ws_size,
                              hipStream_t stream) {
  const float* x     = (const float*)d_in[0];
  const int*   ei    = (const int*)d_in[1];
  const int*   et    = (const int*)d_in[2];
  const float* temp  = (const float*)d_in[3];
  const float* w1    = (const float*)d_in[4];
  const float* b1    = (const float*)d_in[5];
  const float* w2    = (const float*)d_in[6];
  const float* b2    = (const float*)d_in[7];
  const float* comps = (const float*)d_in[8];
  const float* bases = (const float*)d_in[9];
  const float* roots = (const float*)d_in[10];
  const float* cbias = (const float*)d_in[11];

  char* ws = (char*)d_ws;
  size_t off = 0;
  auto take = [&](size_t bytes) {
    char* p = ws + off;
    off = (off + bytes + 255) & ~(size_t)255;
    return p;
  };
  float* wcat    = (float*)take((size_t)L_LAYERS * 128 * 1024 * 4);  // 1.6 MB
  float* invc    = (float*)take((size_t)N_NODES * R_REL * 4);        // int cnt -> fp32 inv, in place
  int*   cntDst  = (int*)take((size_t)N_NODES * 4);
  int*   cursor  = (int*)take((size_t)N_NODES * 4);
  int*   tmpOff  = (int*)take((size_t)N_NODES * 4);
  int*   blockSums = (int*)take((size_t)SCAN_BLOCKS * 4);
  int*   dstStart  = (int*)take((size_t)(N_NODES + 1) * 4);
  int*   epack     = (int*)take((size_t)E_EDGES * 4);                // 2.4 MB
  float* hidden  = (float*)take((size_t)N_NODES * HID * 4);          // 25.6 MB
  float* curA    = (float*)take((size_t)N_NODES * HID * 4);          // 25.6 MB
  float* curB    = (float*)take((size_t)N_NODES * HID * 4);          // 25.6 MB
  unsigned short* Ybf = (unsigned short*)take((size_t)N_NODES * Y_COLS * 2); // 89.6 MB

  hipMemsetAsync(invc, 0, (size_t)N_NODES * R_REL * 4, stream);
  hipMemsetAsync(cntDst, 0, (size_t)N_NODES * 4, stream);
  hipMemsetAsync(cursor, 0, (size_t)N_NODES * 4, stream);

  hipLaunchKernelGGL(build_wcat, dim3((L_LAYERS * 128 * 1024 + 255) / 256),
                     dim3(256), 0, stream, comps, bases, roots, wcat);
  hipLaunchKernelGGL(hist_kernel, dim3((E_EDGES + 255) / 256), dim3(256), 0,
                     stream, ei, et, (int*)invc, cntDst);
  hipLaunchKernelGGL(inv_kernel, dim3((N_NODES * R_REL + 255) / 256), dim3(256),
                     0, stream, invc);
  hipLaunchKernelGGL(scan1_kernel, dim3(SCAN_BLOCKS), dim3(256), 0, stream,
                     cntDst, tmpOff, blockSums);
  hipLaunchKernelGGL(scan2_kernel, dim3(1), dim3(256), 0, stream, blockSums);
  hipLaunchKernelGGL(scan3_kernel, dim3(SCAN_BLOCKS), dim3(256), 0, stream,
                     tmpOff, blockSums, dstStart);
  hipLaunchKernelGGL(place_kernel, dim3((E_EDGES + 255) / 256), dim3(256), 0,
                     stream, ei, et, dstStart, cursor, epack);

  const int rowBlocks = (N_NODES + 127) / 128;   // 391
  hipLaunchKernelGGL((gemm_kernel<IN_C, 0>), dim3(rowBlocks, 1), dim3(256), 0,
                     stream, x, w1, HID, b1, temp, hidden, curA,
                     (unsigned short*)nullptr);

  for (int l = 0; l < L_LAYERS; ++l) {
    hipLaunchKernelGGL((gemm_kernel<HID, 1>), dim3(rowBlocks, M_CAT / 128),
                       dim3(256), 0, stream, curA, wcat + (size_t)l * 128 * 1024,
                       M_CAT, cbias + (size_t)l * HID, temp, curB, (float*)nullptr,
                       Ybf);
    hipLaunchKernelGGL(aggregate_kernel, dim3((N_NODES + 1) / 2), dim3(256), 0,
                       stream, Ybf, epack, dstStart, invc, curB);
    hipLaunchKernelGGL(epilogue_kernel, dim3(N_NODES * HID / 4 / 256), dim3(256),
                       0, stream, curB, hidden, curA, temp, l);
  }

  hipLaunchKernelGGL(final_kernel, dim3((N_NODES + 3) / 4), dim3(256), 0, stream,
                     hidden, w2, b2, (float*)d_out);
}

// Round 4
// 848.101 us; speedup vs baseline: 1.7498x; 1.3380x over previous
//
#include <hip/hip_runtime.h>
#include <cstdint>

// RGPR-GNN (GPR-GNN + RGCN basis-decomp convs) for MI355X.
// R4: bf16 MFMA GEMMs (16x16x32), transform-first RGCN, counting-sort aggregation.
// Per layer:
//   mfma_gemm: curA(bf16)[N,128] @ WcatT(bf16) -> curB(fp32 root+bias) and Ybf(bf16 [N,896])
//   aggregate: block owns dst; curB[dst] += sum_e Y[rel_e][src_e]*inv_cnt(dst,rel_e)
//   epilogue:  c = (l<2 ? relu : id)(curB); hidden += temp[l+1]*c; curA = bf16(c)
// Edge sort (by dst) runs ONCE per call: hist -> 3-kernel exclusive scan -> placement.

constexpr int N_NODES  = 50000;
constexpr int E_EDGES  = 600000;
constexpr int R_REL    = 7;
constexpr int HID      = 128;
constexpr int IN_C     = 256;
constexpr int L_LAYERS = 3;
constexpr int Y_COLS   = 896;           // 7*128 message columns
constexpr int SCAN_BLOCKS = (N_NODES + 255) / 256;   // 196

#define DEVI __device__ __forceinline__

using short8  = __attribute__((ext_vector_type(8))) short;
using floatx4 = __attribute__((ext_vector_type(4))) float;

DEVI unsigned short f2bf(float f) {
  unsigned u = __float_as_uint(f);
  unsigned r = (u + 0x7FFFu + ((u >> 16) & 1u)) >> 16;  // RNE
  return (unsigned short)r;
}
DEVI float bf2f(unsigned short h) { return __uint_as_float(((unsigned)h) << 16); }

// ---------------------------------------------------------------- prep casts
__global__ __launch_bounds__(256) void cast_x_kernel(
    const float* __restrict__ x, unsigned short* __restrict__ xbf)
{
  int i = blockIdx.x * 256 + threadIdx.x;      // over N*IN_C/4
  if (i >= N_NODES * IN_C / 4) return;
  float4 v = ((const float4*)x)[i];
  uint2 p;
  p.x = (unsigned)f2bf(v.x) | ((unsigned)f2bf(v.y) << 16);
  p.y = (unsigned)f2bf(v.z) | ((unsigned)f2bf(v.w) << 16);
  ((uint2*)xbf)[i] = p;
}

__global__ __launch_bounds__(256) void cast_w1_kernel(
    const float* __restrict__ w1, unsigned short* __restrict__ w1T)
{
  int t = blockIdx.x * 256 + threadIdx.x;      // 128*256
  if (t >= HID * IN_C) return;
  int m = t >> 8, k = t & 255;
  w1T[m * IN_C + k] = f2bf(w1[k * HID + m]);
}

// build WcatT bf16: [L][M=1024][K=128]; m<128 -> root^T, else W[r]^T from basis
__global__ __launch_bounds__(256) void build_wcat(
    const float* __restrict__ comps,   // [L,R,8]
    const float* __restrict__ bases,   // [L,8,128,128]
    const float* __restrict__ roots,   // [L,128,128]
    unsigned short* __restrict__ wcatT)
{
  int t = blockIdx.x * 256 + threadIdx.x;
  if (t >= L_LAYERS * 1024 * 128) return;
  int l   = t >> 17;
  int rem = t & 131071;
  int m   = rem >> 7;
  int k   = rem & 127;
  float v;
  if (m < 128) {
    v = roots[((size_t)l * 128 + k) * 128 + m];
  } else {
    int r = (m - 128) >> 7, f = (m - 128) & 127;
    const float* cp = comps + ((size_t)l * R_REL + r) * 8;
    const float* bp = bases + (((size_t)l * 8) * 128 + k) * 128 + f;
    float s = 0.f;
#pragma unroll
    for (int b = 0; b < 8; ++b) s += cp[b] * bp[(size_t)b * 128 * 128];
    v = s;
  }
  wcatT[t] = f2bf(v);
}

// ---------------------------------------------------------------- histograms
__global__ __launch_bounds__(256) void hist_kernel(
    const int* __restrict__ ei, const int* __restrict__ et,
    int* __restrict__ cntRel, int* __restrict__ cntDst)
{
  int e = blockIdx.x * 256 + threadIdx.x;
  if (e >= E_EDGES) return;
  int dst = ei[E_EDGES + e];
  atomicAdd(&cntRel[dst * R_REL + et[e]], 1);
  atomicAdd(&cntDst[dst], 1);
}

__global__ __launch_bounds__(256) void inv_kernel(float* __restrict__ invc)
{
  int s = blockIdx.x * 256 + threadIdx.x;
  if (s >= N_NODES * R_REL) return;
  int c = ((const int*)invc)[s];
  if (c < 1) c = 1;
  invc[s] = 1.0f / (float)c;
}

// ---------------------------------------------------------------- scan (3-kernel)
__global__ __launch_bounds__(256) void scan1_kernel(
    const int* __restrict__ cntDst, int* __restrict__ tmpOff,
    int* __restrict__ blockSums)
{
  __shared__ int s[256];
  int i = blockIdx.x * 256 + threadIdx.x;
  int v = (i < N_NODES) ? cntDst[i] : 0;
  s[threadIdx.x] = v;
  __syncthreads();
#pragma unroll
  for (int d = 1; d < 256; d <<= 1) {
    int t = (threadIdx.x >= d) ? s[threadIdx.x - d] : 0;
    __syncthreads();
    s[threadIdx.x] += t;
    __syncthreads();
  }
  if (i < N_NODES) tmpOff[i] = s[threadIdx.x] - v;
  if (threadIdx.x == 255) blockSums[blockIdx.x] = s[255];
}

__global__ __launch_bounds__(256) void scan2_kernel(int* __restrict__ blockSums)
{
  __shared__ int s[256];
  int v = (threadIdx.x < SCAN_BLOCKS) ? blockSums[threadIdx.x] : 0;
  s[threadIdx.x] = v;
  __syncthreads();
#pragma unroll
  for (int d = 1; d < 256; d <<= 1) {
    int t = (threadIdx.x >= d) ? s[threadIdx.x - d] : 0;
    __syncthreads();
    s[threadIdx.x] += t;
    __syncthreads();
  }
  if (threadIdx.x < SCAN_BLOCKS) blockSums[threadIdx.x] = s[threadIdx.x] - v;
}

__global__ __launch_bounds__(256) void scan3_kernel(
    const int* __restrict__ tmpOff, const int* __restrict__ blockSums,
    int* __restrict__ dstStart)
{
  int i = blockIdx.x * 256 + threadIdx.x;
  if (i < N_NODES) dstStart[i] = tmpOff[i] + blockSums[blockIdx.x];
  if (i == 0) dstStart[N_NODES] = E_EDGES;
}

// ---------------------------------------------------------------- placement
__global__ __launch_bounds__(256) void place_kernel(
    const int* __restrict__ ei, const int* __restrict__ et,
    const int* __restrict__ dstStart, int* __restrict__ cursor,
    int* __restrict__ epack)
{
  int e = blockIdx.x * 256 + threadIdx.x;
  if (e >= E_EDGES) return;
  int src = ei[e], dst = ei[E_EDGES + e], r = et[e];
  int pos = dstStart[dst] + atomicAdd(&cursor[dst], 1);
  epack[pos] = src | (r << 16);   // src < 65536, r < 8
}

// ---------------------------------------------------------------- MFMA GEMM
// 128x128 tile per block, 256 threads = 4 waves, each wave 64x64 (4x4 of 16x16x32).
// A [N,KDIM] bf16 row-major; BT [M,KDIM] bf16 (pre-transposed weights).
// EPI 0 (lin1):  out0=hidden fp32 = t0*(acc+bias); outT=curA bf16 (same value). grid(1,391)
// EPI 1 (layer): bx==0 -> out0=curB fp32 = acc+bias; bx>0 -> outT=Ybf[(bx-1)*128+..] bf16. grid(8,391)
template <int KDIM, int EPI>
__global__ __launch_bounds__(256) void mfma_gemm(
    const unsigned short* __restrict__ A,
    const unsigned short* __restrict__ BT,
    const float* __restrict__ bias,
    const float* __restrict__ temp,
    float* __restrict__ out0,
    unsigned short* __restrict__ outT)
{
  __shared__ unsigned short As[128][136];   // +8 bf16 pad: 2-way banks on b128 reads
  __shared__ unsigned short Bs[128][136];

  const int tid  = threadIdx.x;
  const int bx   = blockIdx.x;
  const int row0 = blockIdx.y * 128;
  const int col0 = bx * 128;
  const int lane = tid & 63;
  const int wid  = tid >> 6;
  const int wrow = (wid & 1) * 64;
  const int wcol = (wid >> 1) * 64;
  const int l15  = lane & 15;
  const int quad = lane >> 4;

  floatx4 acc[4][4] = {};

  for (int k0 = 0; k0 < KDIM; k0 += 128) {
#pragma unroll
    for (int it = 0; it < 8; ++it) {
      int chunk = it * 256 + tid;
      int r = chunk >> 4, cc = (chunk & 15) << 3;   // 16 chunks of 8 bf16 per row
      int grow = row0 + r;
      uint4 va = make_uint4(0u, 0u, 0u, 0u);
      if (grow < N_NODES)
        va = *(const uint4*)(A + (size_t)grow * KDIM + k0 + cc);
      *(uint4*)(&As[r][cc]) = va;
      *(uint4*)(&Bs[r][cc]) =
          *(const uint4*)(BT + (size_t)(col0 + r) * KDIM + k0 + cc);
    }
    __syncthreads();
#pragma unroll
    for (int ks = 0; ks < 4; ++ks) {
      int kc = ks * 32 + quad * 8;
      short8 af[4], bfr[4];
#pragma unroll
      for (int i = 0; i < 4; ++i)
        af[i] = *(const short8*)(&As[wrow + i * 16 + l15][kc]);
#pragma unroll
      for (int j = 0; j < 4; ++j)
        bfr[j] = *(const short8*)(&Bs[wcol + j * 16 + l15][kc]);
#pragma unroll
      for (int i = 0; i < 4; ++i)
#pragma unroll
        for (int j = 0; j < 4; ++j)
          acc[i][j] = __builtin_amdgcn_mfma_f32_16x16x32_bf16(
              af[i], bfr[j], acc[i][j], 0, 0, 0);
    }
    __syncthreads();
  }

  // C/D layout: col = lane&15, row = quad*4 + reg   [verified m89/m91]
  if (EPI == 0) {
    float t0 = temp[0];
#pragma unroll
    for (int i = 0; i < 4; ++i) {
      int lrow0 = wrow + i * 16 + quad * 4;
#pragma unroll
      for (int j = 0; j < 4; ++j) {
        int gcol = wcol + j * 16 + l15;
        float bb = bias[gcol];
#pragma unroll
        for (int r = 0; r < 4; ++r) {
          float v = t0 * (acc[i][j][r] + bb);
          int grow = row0 + lrow0 + r;
          if (grow < N_NODES) out0[(size_t)grow * HID + gcol] = v;
          As[lrow0 + r][gcol] = f2bf(v);
        }
      }
    }
    __syncthreads();
#pragma unroll
    for (int it = 0; it < 8; ++it) {
      int chunk = it * 256 + tid;
      int r = chunk >> 4, cc = (chunk & 15) << 3;
      int grow = row0 + r;
      if (grow < N_NODES)
        *(uint4*)(outT + (size_t)grow * HID + cc) = *(const uint4*)(&As[r][cc]);
    }
  } else if (bx == 0) {
#pragma unroll
    for (int i = 0; i < 4; ++i) {
      int lrow0 = wrow + i * 16 + quad * 4;
#pragma unroll
      for (int j = 0; j < 4; ++j) {
        int gcol = wcol + j * 16 + l15;
        float bb = bias[gcol];
#pragma unroll
        for (int r = 0; r < 4; ++r) {
          int grow = row0 + lrow0 + r;
          if (grow < N_NODES)
            out0[(size_t)grow * HID + gcol] = acc[i][j][r] + bb;
        }
      }
    }
  } else {
#pragma unroll
    for (int i = 0; i < 4; ++i) {
      int lrow0 = wrow + i * 16 + quad * 4;
#pragma unroll
      for (int j = 0; j < 4; ++j) {
        int lcol = wcol + j * 16 + l15;
#pragma unroll
        for (int r = 0; r < 4; ++r)
          As[lrow0 + r][lcol] = f2bf(acc[i][j][r]);
      }
    }
    __syncthreads();
    const int ycol0 = (bx - 1) * 128;
#pragma unroll
    for (int it = 0; it < 8; ++it) {
      int chunk = it * 256 + tid;
      int r = chunk >> 4, cc = (chunk & 15) << 3;
      int grow = row0 + r;
      if (grow < N_NODES)
        *(uint4*)(outT + (size_t)grow * Y_COLS + ycol0 + cc) =
            *(const uint4*)(&As[r][cc]);
    }
  }
}

// ---------------------------------------------------------------- segment aggregate
// Block = 256 threads = 2 dsts x 128 dims. One block owns its dsts: no atomics.
__global__ __launch_bounds__(256) void aggregate_kernel(
    const unsigned short* __restrict__ Y,
    const int* __restrict__ epack,
    const int* __restrict__ dstStart,
    const float* __restrict__ invc,
    float* __restrict__ curB)
{
  int dst = blockIdx.x * 2 + (threadIdx.x >> 7);
  if (dst >= N_NODES) return;
  int d = threadIdx.x & 127;
  int p0 = dstStart[dst], p1 = dstStart[dst + 1];
  float acc = 0.f;
  for (int p = p0; p < p1; ++p) {
    int pk = epack[p];
    int src = pk & 0xFFFF;
    int r   = pk >> 16;
    acc += bf2f(Y[(size_t)src * Y_COLS + r * 128 + d]) * invc[dst * R_REL + r];
  }
  curB[(size_t)dst * HID + d] += acc;
}

// ---------------------------------------------------------------- epilogue
__global__ __launch_bounds__(256) void epilogue_kernel(
    const float* __restrict__ curB, float* __restrict__ hidden,
    unsigned short* __restrict__ curA, const float* __restrict__ temp, int layer)
{
  int i = blockIdx.x * 256 + threadIdx.x;   // over N*HID/4
  if (i >= N_NODES * HID / 4) return;
  float tl = temp[layer + 1];
  float4 c = ((const float4*)curB)[i];
  if (layer < L_LAYERS - 1) {
    c.x = fmaxf(c.x, 0.f); c.y = fmaxf(c.y, 0.f);
    c.z = fmaxf(c.z, 0.f); c.w = fmaxf(c.w, 0.f);
  }
  float4 h = ((const float4*)hidden)[i];
  h.x += tl * c.x; h.y += tl * c.y; h.z += tl * c.z; h.w += tl * c.w;
  ((float4*)hidden)[i] = h;
  if (layer < L_LAYERS - 1) {
    uint2 p;
    p.x = (unsigned)f2bf(c.x) | ((unsigned)f2bf(c.y) << 16);
    p.y = (unsigned)f2bf(c.z) | ((unsigned)f2bf(c.w) << 16);
    ((uint2*)curA)[i] = p;
  }
}

// ---------------------------------------------------------------- final linear
__global__ __launch_bounds__(256) void final_kernel(
    const float* __restrict__ hidden, const float* __restrict__ w2,
    const float* __restrict__ b2, float* __restrict__ out)
{
  int node = blockIdx.x * 4 + (threadIdx.x >> 6);
  int lane = threadIdx.x & 63;
  if (node >= N_NODES) return;
  float h0 = hidden[(size_t)node * HID + lane];
  float h1 = hidden[(size_t)node * HID + 64 + lane];
  float a0 = h0 * w2[lane * 2 + 0] + h1 * w2[(lane + 64) * 2 + 0];
  float a1 = h0 * w2[lane * 2 + 1] + h1 * w2[(lane + 64) * 2 + 1];
#pragma unroll
  for (int off = 32; off > 0; off >>= 1) {
    a0 += __shfl_down(a0, off);
    a1 += __shfl_down(a1, off);
  }
  if (lane == 0) {
    out[node * 2 + 0] = a0 + b2[0];
    out[node * 2 + 1] = a1 + b2[1];
  }
}

// ---------------------------------------------------------------- launcher
extern "C" void kernel_launch(void* const* d_in, const int* in_sizes, int n_in,
                              void* d_out, int out_size, void* d_ws, size_t ws_size,
                              hipStream_t stream) {
  const float* x     = (const float*)d_in[0];
  const int*   ei    = (const int*)d_in[1];
  const int*   et    = (const int*)d_in[2];
  const float* temp  = (const float*)d_in[3];
  const float* w1    = (const float*)d_in[4];
  const float* b1    = (const float*)d_in[5];
  const float* w2    = (const float*)d_in[6];
  const float* b2    = (const float*)d_in[7];
  const float* comps = (const float*)d_in[8];
  const float* bases = (const float*)d_in[9];
  const float* roots = (const float*)d_in[10];
  const float* cbias = (const float*)d_in[11];

  char* ws = (char*)d_ws;
  size_t off = 0;
  auto take = [&](size_t bytes) {
    char* p = ws + off;
    off = (off + bytes + 255) & ~(size_t)255;
    return p;
  };
  unsigned short* wcatT = (unsigned short*)take((size_t)L_LAYERS * 1024 * 128 * 2); // 0.8 MB
  unsigned short* xbf   = (unsigned short*)take((size_t)N_NODES * IN_C * 2);        // 25.6 MB
  unsigned short* w1T   = (unsigned short*)take((size_t)HID * IN_C * 2);            // 64 KB
  float* invc    = (float*)take((size_t)N_NODES * R_REL * 4);   // int cnt -> fp32 inv, in place
  int*   cntDst  = (int*)take((size_t)N_NODES * 4);
  int*   cursor  = (int*)take((size_t)N_NODES * 4);
  int*   tmpOff  = (int*)take((size_t)N_NODES * 4);
  int*   blockSums = (int*)take((size_t)SCAN_BLOCKS * 4);
  int*   dstStart  = (int*)take((size_t)(N_NODES + 1) * 4);
  int*   epack     = (int*)take((size_t)E_EDGES * 4);           // 2.4 MB
  float* hidden  = (float*)take((size_t)N_NODES * HID * 4);     // 25.6 MB
  unsigned short* curA = (unsigned short*)take((size_t)N_NODES * HID * 2); // 12.8 MB
  float* curB    = (float*)take((size_t)N_NODES * HID * 4);     // 25.6 MB
  unsigned short* Ybf = (unsigned short*)take((size_t)N_NODES * Y_COLS * 2); // 89.6 MB

  hipMemsetAsync(invc, 0, (size_t)N_NODES * R_REL * 4, stream);
  hipMemsetAsync(cntDst, 0, (size_t)N_NODES * 4, stream);
  hipMemsetAsync(cursor, 0, (size_t)N_NODES * 4, stream);

  hipLaunchKernelGGL(build_wcat, dim3((L_LAYERS * 1024 * 128 + 255) / 256),
                     dim3(256), 0, stream, comps, bases, roots, wcatT);
  hipLaunchKernelGGL(cast_x_kernel, dim3((N_NODES * IN_C / 4 + 255) / 256),
                     dim3(256), 0, stream, x, xbf);
  hipLaunchKernelGGL(cast_w1_kernel, dim3((HID * IN_C + 255) / 256), dim3(256),
                     0, stream, w1, w1T);
  hipLaunchKernelGGL(hist_kernel, dim3((E_EDGES + 255) / 256), dim3(256), 0,
                     stream, ei, et, (int*)invc, cntDst);
  hipLaunchKernelGGL(inv_kernel, dim3((N_NODES * R_REL + 255) / 256), dim3(256),
                     0, stream, invc);
  hipLaunchKernelGGL(scan1_kernel, dim3(SCAN_BLOCKS), dim3(256), 0, stream,
                     cntDst, tmpOff, blockSums);
  hipLaunchKernelGGL(scan2_kernel, dim3(1), dim3(256), 0, stream, blockSums);
  hipLaunchKernelGGL(scan3_kernel, dim3(SCAN_BLOCKS), dim3(256), 0, stream,
                     tmpOff, blockSums, dstStart);
  hipLaunchKernelGGL(place_kernel, dim3((E_EDGES + 255) / 256), dim3(256), 0,
                     stream, ei, et, dstStart, cursor, epack);

  const int rowBlocks = (N_NODES + 127) / 128;   // 391
  // lin1: hidden = t0*(x@w1+b1) fp32, curA = bf16(same)
  hipLaunchKernelGGL((mfma_gemm<IN_C, 0>), dim3(1, rowBlocks), dim3(256), 0,
                     stream, xbf, w1T, b1, temp, hidden, curA);

  for (int l = 0; l < L_LAYERS; ++l) {
    hipLaunchKernelGGL((mfma_gemm<HID, 1>), dim3(8, rowBlocks), dim3(256), 0,
                       stream, curA, wcatT + (size_t)l * 1024 * 128,
                       cbias + (size_t)l * HID, temp, curB, Ybf);
    hipLaunchKernelGGL(aggregate_kernel, dim3((N_NODES + 1) / 2), dim3(256), 0,
                       stream, Ybf, epack, dstStart, invc, curB);
    hipLaunchKernelGGL(epilogue_kernel, dim3(N_NODES * HID / 4 / 256), dim3(256),
                       0, stream, curB, hidden, curA, temp, l);
  }

  hipLaunchKernelGGL(final_kernel, dim3((N_NODES + 3) / 4), dim3(256), 0, stream,
                     hidden, w2, b2, (float*)d_out);
}

// Round 5
// 591.229 us; speedup vs baseline: 2.5101x; 1.4345x over previous
//
#include <hip/hip_runtime.h>
#include <cstdint>

// RGPR-GNN (GPR-GNN + RGCN basis-decomp convs) for MI355X.
// R5: AGGREGATE-FIRST. Aggregation is linear, so per layer:
//   agg2:      agg[dst][r][d] = mean over edges(dst,r) of curA[src][d]   (bf16 out, fp32 LDS accum)
//   gemm_layer: curB = [curA | agg] (K=1024) @ Wcat2[1024,128] + bias    (bf16 MFMA 16x16x32)
//   epilogue:  c = (l<2 ? relu : id)(curB); hidden += temp[l+1]*c; curA = bf16(c)
// This kills the Y[N,896] materialization (90MB write + 90MB HBM re-fetch per layer);
// the gather source is curA (12.8 MB, L2/LLC-hot) instead of Y (89.6 MB, LLC-only).
// Edge sort (by dst) runs ONCE per call: hist -> 3-kernel exclusive scan -> placement.

constexpr int N_NODES  = 50000;
constexpr int E_EDGES  = 600000;
constexpr int R_REL    = 7;
constexpr int HID      = 128;
constexpr int IN_C     = 256;
constexpr int L_LAYERS = 3;
constexpr int AGG_COLS = 896;           // 7*128 aggregated message columns
constexpr int K_CAT    = 1024;          // 128 self + 896 agg
constexpr int SCAN_BLOCKS = (N_NODES + 255) / 256;   // 196

#define DEVI __device__ __forceinline__

using short8  = __attribute__((ext_vector_type(8))) short;
using floatx4 = __attribute__((ext_vector_type(4))) float;

DEVI unsigned short f2bf(float f) {
  unsigned u = __float_as_uint(f);
  unsigned r = (u + 0x7FFFu + ((u >> 16) & 1u)) >> 16;  // RNE
  return (unsigned short)r;
}
DEVI float bf2f(unsigned short h) { return __uint_as_float(((unsigned)h) << 16); }

// ---------------------------------------------------------------- prep casts
__global__ __launch_bounds__(256) void cast_x_kernel(
    const float* __restrict__ x, unsigned short* __restrict__ xbf)
{
  int i = blockIdx.x * 256 + threadIdx.x;      // over N*IN_C/4
  if (i >= N_NODES * IN_C / 4) return;
  float4 v = ((const float4*)x)[i];
  uint2 p;
  p.x = (unsigned)f2bf(v.x) | ((unsigned)f2bf(v.y) << 16);
  p.y = (unsigned)f2bf(v.z) | ((unsigned)f2bf(v.w) << 16);
  ((uint2*)xbf)[i] = p;
}

__global__ __launch_bounds__(256) void cast_w1_kernel(
    const float* __restrict__ w1, unsigned short* __restrict__ w1T)
{
  int t = blockIdx.x * 256 + threadIdx.x;      // 128*256
  if (t >= HID * IN_C) return;
  int m = t >> 8, k = t & 255;
  w1T[m * IN_C + k] = f2bf(w1[k * HID + m]);
}

// Wcat2T bf16: [L][f=128][k=1024]. k<128 -> roots[l][k][f]; k>=128 -> W[r][d][f]
// (r=(k-128)>>7, d=(k-128)&127, W=sum_b comp*basis). Rows are OUTPUT cols (B^T layout).
__global__ __launch_bounds__(256) void build_wcat2(
    const float* __restrict__ comps,   // [L,R,8]
    const float* __restrict__ bases,   // [L,8,128,128]
    const float* __restrict__ roots,   // [L,128,128]
    unsigned short* __restrict__ wcat2T)
{
  int t = blockIdx.x * 256 + threadIdx.x;
  if (t >= L_LAYERS * 128 * K_CAT) return;
  int l   = t >> 17;
  int rem = t & 131071;
  int f   = rem >> 10;
  int k   = rem & 1023;
  float v;
  if (k < 128) {
    v = roots[((size_t)l * 128 + k) * 128 + f];
  } else {
    int r = (k - 128) >> 7, d = (k - 128) & 127;
    const float* cp = comps + ((size_t)l * R_REL + r) * 8;
    const float* bp = bases + (((size_t)l * 8) * 128 + d) * 128 + f;
    float s = 0.f;
#pragma unroll
    for (int b = 0; b < 8; ++b) s += cp[b] * bp[(size_t)b * 128 * 128];
    v = s;
  }
  wcat2T[t] = f2bf(v);
}

// ---------------------------------------------------------------- histograms
__global__ __launch_bounds__(256) void hist_kernel(
    const int* __restrict__ ei, const int* __restrict__ et,
    int* __restrict__ cntRel, int* __restrict__ cntDst)
{
  int e = blockIdx.x * 256 + threadIdx.x;
  if (e >= E_EDGES) return;
  int dst = ei[E_EDGES + e];
  atomicAdd(&cntRel[dst * R_REL + et[e]], 1);
  atomicAdd(&cntDst[dst], 1);
}

__global__ __launch_bounds__(256) void inv_kernel(float* __restrict__ invc)
{
  int s = blockIdx.x * 256 + threadIdx.x;
  if (s >= N_NODES * R_REL) return;
  int c = ((const int*)invc)[s];
  if (c < 1) c = 1;
  invc[s] = 1.0f / (float)c;
}

// ---------------------------------------------------------------- scan (3-kernel)
__global__ __launch_bounds__(256) void scan1_kernel(
    const int* __restrict__ cntDst, int* __restrict__ tmpOff,
    int* __restrict__ blockSums)
{
  __shared__ int s[256];
  int i = blockIdx.x * 256 + threadIdx.x;
  int v = (i < N_NODES) ? cntDst[i] : 0;
  s[threadIdx.x] = v;
  __syncthreads();
#pragma unroll
  for (int d = 1; d < 256; d <<= 1) {
    int t = (threadIdx.x >= d) ? s[threadIdx.x - d] : 0;
    __syncthreads();
    s[threadIdx.x] += t;
    __syncthreads();
  }
  if (i < N_NODES) tmpOff[i] = s[threadIdx.x] - v;
  if (threadIdx.x == 255) blockSums[blockIdx.x] = s[255];
}

__global__ __launch_bounds__(256) void scan2_kernel(int* __restrict__ blockSums)
{
  __shared__ int s[256];
  int v = (threadIdx.x < SCAN_BLOCKS) ? blockSums[threadIdx.x] : 0;
  s[threadIdx.x] = v;
  __syncthreads();
#pragma unroll
  for (int d = 1; d < 256; d <<= 1) {
    int t = (threadIdx.x >= d) ? s[threadIdx.x - d] : 0;
    __syncthreads();
    s[threadIdx.x] += t;
    __syncthreads();
  }
  if (threadIdx.x < SCAN_BLOCKS) blockSums[threadIdx.x] = s[threadIdx.x] - v;
}

__global__ __launch_bounds__(256) void scan3_kernel(
    const int* __restrict__ tmpOff, const int* __restrict__ blockSums,
    int* __restrict__ dstStart)
{
  int i = blockIdx.x * 256 + threadIdx.x;
  if (i < N_NODES) dstStart[i] = tmpOff[i] + blockSums[blockIdx.x];
  if (i == 0) dstStart[N_NODES] = E_EDGES;
}

// ---------------------------------------------------------------- placement
__global__ __launch_bounds__(256) void place_kernel(
    const int* __restrict__ ei, const int* __restrict__ et,
    const int* __restrict__ dstStart, int* __restrict__ cursor,
    int* __restrict__ epack)
{
  int e = blockIdx.x * 256 + threadIdx.x;
  if (e >= E_EDGES) return;
  int src = ei[e], dst = ei[E_EDGES + e], r = et[e];
  int pos = dstStart[dst] + atomicAdd(&cursor[dst], 1);
  epack[pos] = src | (r << 16);   // src < 65536, r < 8
}

// ---------------------------------------------------------------- aggregate-first
// Block = 256 = 4 waves, one dst per wave. 64 lanes x 2 dims (uint = 2 bf16).
// fp32 accumulation in LDS (b64 RMW, conflict-free); mean scale folded into
// the vectorized bf16 writeout. epack broadcast via __shfl (no LDS, no atomics).
__global__ __launch_bounds__(256) void agg2_kernel(
    const unsigned short* __restrict__ curA,   // [N,128] bf16
    const int* __restrict__ epack,
    const int* __restrict__ dstStart,
    const float* __restrict__ invc,
    unsigned short* __restrict__ aggB)         // [N,896] bf16
{
  __shared__ float accF[4][AGG_COLS];          // 14.3 KB
  const int tid  = threadIdx.x;
  const int w    = tid >> 6;
  const int lane = tid & 63;
  const int dst0 = blockIdx.x * 4;
  const int dst  = dst0 + w;

  for (int i = tid; i < 4 * AGG_COLS; i += 256) ((float*)accF)[i] = 0.f;
  __syncthreads();

  int p0 = dstStart[dst], p1 = dstStart[dst + 1];
  for (int p = p0; p < p1; p += 64) {
    int m = p1 - p; if (m > 64) m = 64;
    int pk_l = (lane < m) ? epack[p + lane] : 0;
    for (int i = 0; i < m; ++i) {
      int pk  = __shfl(pk_l, i);
      int src = pk & 0xFFFF;
      int r   = pk >> 16;
      unsigned v = *(const unsigned*)(curA + (size_t)src * HID + lane * 2);
      float2* ap = (float2*)&accF[w][r * HID + lane * 2];
      float2 a = *ap;
      a.x += bf2f((unsigned short)(v & 0xFFFF));
      a.y += bf2f((unsigned short)(v >> 16));
      *ap = a;
    }
  }
  __syncthreads();

  // writeout: 4 dsts x 112 chunks of 8 bf16, mean-scaled; coalesced uint4 stores
  for (int c = tid; c < 4 * (AGG_COLS / 8); c += 256) {
    int dl  = c / 112;
    int cin = c - dl * 112;
    int d0  = cin * 8;
    int r   = d0 >> 7;
    float sc = invc[(dst0 + dl) * R_REL + r];
    const float* ap = &accF[dl][d0];
    uint4 pck;
    pck.x = (unsigned)f2bf(ap[0] * sc) | ((unsigned)f2bf(ap[1] * sc) << 16);
    pck.y = (unsigned)f2bf(ap[2] * sc) | ((unsigned)f2bf(ap[3] * sc) << 16);
    pck.z = (unsigned)f2bf(ap[4] * sc) | ((unsigned)f2bf(ap[5] * sc) << 16);
    pck.w = (unsigned)f2bf(ap[6] * sc) | ((unsigned)f2bf(ap[7] * sc) << 16);
    *(uint4*)(aggB + (size_t)(dst0 + dl) * AGG_COLS + d0) = pck;
  }
}

// ---------------------------------------------------------------- lin1 MFMA GEMM
// 128x128 tile, K=256: hidden = t0*(x@w1+b1) fp32, curA = bf16(same). grid(391).
__global__ __launch_bounds__(256) void gemm_lin1(
    const unsigned short* __restrict__ A,     // xbf [N,256]
    const unsigned short* __restrict__ BT,    // w1T [128,256]
    const float* __restrict__ bias,
    const float* __restrict__ temp,
    float* __restrict__ out0,                 // hidden fp32
    unsigned short* __restrict__ outT)        // curA bf16
{
  __shared__ unsigned short As[128][136];
  __shared__ unsigned short Bs[128][136];
  const int tid  = threadIdx.x;
  const int row0 = blockIdx.x * 128;
  const int lane = tid & 63;
  const int wid  = tid >> 6;
  const int wrow = (wid & 1) * 64;
  const int wcol = (wid >> 1) * 64;
  const int l15  = lane & 15;
  const int quad = lane >> 4;

  floatx4 acc[4][4] = {};

  for (int k0 = 0; k0 < IN_C; k0 += 128) {
#pragma unroll
    for (int it = 0; it < 8; ++it) {
      int chunk = it * 256 + tid;
      int r = chunk >> 4, cc = (chunk & 15) << 3;
      int grow = row0 + r;
      uint4 va = make_uint4(0u, 0u, 0u, 0u);
      if (grow < N_NODES)
        va = *(const uint4*)(A + (size_t)grow * IN_C + k0 + cc);
      *(uint4*)(&As[r][cc]) = va;
      *(uint4*)(&Bs[r][cc]) = *(const uint4*)(BT + (size_t)r * IN_C + k0 + cc);
    }
    __syncthreads();
#pragma unroll
    for (int ks = 0; ks < 4; ++ks) {
      int kc = ks * 32 + quad * 8;
      short8 af[4], bfr[4];
#pragma unroll
      for (int i = 0; i < 4; ++i)
        af[i] = *(const short8*)(&As[wrow + i * 16 + l15][kc]);
#pragma unroll
      for (int j = 0; j < 4; ++j)
        bfr[j] = *(const short8*)(&Bs[wcol + j * 16 + l15][kc]);
#pragma unroll
      for (int i = 0; i < 4; ++i)
#pragma unroll
        for (int j = 0; j < 4; ++j)
          acc[i][j] = __builtin_amdgcn_mfma_f32_16x16x32_bf16(
              af[i], bfr[j], acc[i][j], 0, 0, 0);
    }
    __syncthreads();
  }

  // C/D layout: col = lane&15, row = quad*4 + reg
  float t0 = temp[0];
#pragma unroll
  for (int i = 0; i < 4; ++i) {
    int lrow0 = wrow + i * 16 + quad * 4;
#pragma unroll
    for (int j = 0; j < 4; ++j) {
      int gcol = wcol + j * 16 + l15;
      float bb = bias[gcol];
#pragma unroll
      for (int r = 0; r < 4; ++r) {
        float v = t0 * (acc[i][j][r] + bb);
        int grow = row0 + lrow0 + r;
        if (grow < N_NODES) out0[(size_t)grow * HID + gcol] = v;
        As[lrow0 + r][gcol] = f2bf(v);
      }
    }
  }
  __syncthreads();
#pragma unroll
  for (int it = 0; it < 8; ++it) {
    int chunk = it * 256 + tid;
    int r = chunk >> 4, cc = (chunk & 15) << 3;
    int grow = row0 + r;
    if (grow < N_NODES)
      *(uint4*)(outT + (size_t)grow * HID + cc) = *(const uint4*)(&As[r][cc]);
  }
}

// ---------------------------------------------------------------- layer MFMA GEMM
// 128x128 tile, K=1024 dual-source A = [curA (k<128) | aggB (k>=128)].
// curB = A @ Wcat2T^T + bias (fp32). grid(391).
__global__ __launch_bounds__(256) void gemm_layer(
    const unsigned short* __restrict__ curA,   // [N,128] bf16
    const unsigned short* __restrict__ aggB,   // [N,896] bf16
    const unsigned short* __restrict__ BT,     // wcat2T [128][1024] bf16
    const float* __restrict__ bias,
    float* __restrict__ out0)                  // curB fp32
{
  __shared__ unsigned short As[128][136];
  __shared__ unsigned short Bs[128][136];
  const int tid  = threadIdx.x;
  const int row0 = blockIdx.x * 128;
  const int lane = tid & 63;
  const int wid  = tid >> 6;
  const int wrow = (wid & 1) * 64;
  const int wcol = (wid >> 1) * 64;
  const int l15  = lane & 15;
  const int quad = lane >> 4;

  floatx4 acc[4][4] = {};

  for (int k0 = 0; k0 < K_CAT; k0 += 128) {
#pragma unroll
    for (int it = 0; it < 8; ++it) {
      int chunk = it * 256 + tid;
      int r = chunk >> 4, cc = (chunk & 15) << 3;
      int grow = row0 + r;
      uint4 va = make_uint4(0u, 0u, 0u, 0u);
      if (grow < N_NODES) {
        if (k0 == 0)
          va = *(const uint4*)(curA + (size_t)grow * HID + cc);
        else
          va = *(const uint4*)(aggB + (size_t)grow * AGG_COLS + (k0 - 128) + cc);
      }
      *(uint4*)(&As[r][cc]) = va;
      *(uint4*)(&Bs[r][cc]) = *(const uint4*)(BT + (size_t)r * K_CAT + k0 + cc);
    }
    __syncthreads();
#pragma unroll
    for (int ks = 0; ks < 4; ++ks) {
      int kc = ks * 32 + quad * 8;
      short8 af[4], bfr[4];
#pragma unroll
      for (int i = 0; i < 4; ++i)
        af[i] = *(const short8*)(&As[wrow + i * 16 + l15][kc]);
#pragma unroll
      for (int j = 0; j < 4; ++j)
        bfr[j] = *(const short8*)(&Bs[wcol + j * 16 + l15][kc]);
#pragma unroll
      for (int i = 0; i < 4; ++i)
#pragma unroll
        for (int j = 0; j < 4; ++j)
          acc[i][j] = __builtin_amdgcn_mfma_f32_16x16x32_bf16(
              af[i], bfr[j], acc[i][j], 0, 0, 0);
    }
    __syncthreads();
  }

#pragma unroll
  for (int i = 0; i < 4; ++i) {
    int lrow0 = wrow + i * 16 + quad * 4;
#pragma unroll
    for (int j = 0; j < 4; ++j) {
      int gcol = wcol + j * 16 + l15;
      float bb = bias[gcol];
#pragma unroll
      for (int r = 0; r < 4; ++r) {
        int grow = row0 + lrow0 + r;
        if (grow < N_NODES)
          out0[(size_t)grow * HID + gcol] = acc[i][j][r] + bb;
      }
    }
  }
}

// ---------------------------------------------------------------- epilogue
__global__ __launch_bounds__(256) void epilogue_kernel(
    const float* __restrict__ curB, float* __restrict__ hidden,
    unsigned short* __restrict__ curA, const float* __restrict__ temp, int layer)
{
  int i = blockIdx.x * 256 + threadIdx.x;   // over N*HID/4
  if (i >= N_NODES * HID / 4) return;
  float tl = temp[layer + 1];
  float4 c = ((const float4*)curB)[i];
  if (layer < L_LAYERS - 1) {
    c.x = fmaxf(c.x, 0.f); c.y = fmaxf(c.y, 0.f);
    c.z = fmaxf(c.z, 0.f); c.w = fmaxf(c.w, 0.f);
  }
  float4 h = ((const float4*)hidden)[i];
  h.x += tl * c.x; h.y += tl * c.y; h.z += tl * c.z; h.w += tl * c.w;
  ((float4*)hidden)[i] = h;
  if (layer < L_LAYERS - 1) {
    uint2 p;
    p.x = (unsigned)f2bf(c.x) | ((unsigned)f2bf(c.y) << 16);
    p.y = (unsigned)f2bf(c.z) | ((unsigned)f2bf(c.w) << 16);
    ((uint2*)curA)[i] = p;
  }
}

// ---------------------------------------------------------------- final linear
__global__ __launch_bounds__(256) void final_kernel(
    const float* __restrict__ hidden, const float* __restrict__ w2,
    const float* __restrict__ b2, float* __restrict__ out)
{
  int node = blockIdx.x * 4 + (threadIdx.x >> 6);
  int lane = threadIdx.x & 63;
  if (node >= N_NODES) return;
  float h0 = hidden[(size_t)node * HID + lane];
  float h1 = hidden[(size_t)node * HID + 64 + lane];
  float a0 = h0 * w2[lane * 2 + 0] + h1 * w2[(lane + 64) * 2 + 0];
  float a1 = h0 * w2[lane * 2 + 1] + h1 * w2[(lane + 64) * 2 + 1];
#pragma unroll
  for (int off = 32; off > 0; off >>= 1) {
    a0 += __shfl_down(a0, off);
    a1 += __shfl_down(a1, off);
  }
  if (lane == 0) {
    out[node * 2 + 0] = a0 + b2[0];
    out[node * 2 + 1] = a1 + b2[1];
  }
}

// ---------------------------------------------------------------- launcher
extern "C" void kernel_launch(void* const* d_in, const int* in_sizes, int n_in,
                              void* d_out, int out_size, void* d_ws, size_t ws_size,
                              hipStream_t stream) {
  const float* x     = (const float*)d_in[0];
  const int*   ei    = (const int*)d_in[1];
  const int*   et    = (const int*)d_in[2];
  const float* temp  = (const float*)d_in[3];
  const float* w1    = (const float*)d_in[4];
  const float* b1    = (const float*)d_in[5];
  const float* w2    = (const float*)d_in[6];
  const float* b2    = (const float*)d_in[7];
  const float* comps = (const float*)d_in[8];
  const float* bases = (const float*)d_in[9];
  const float* roots = (const float*)d_in[10];
  const float* cbias = (const float*)d_in[11];

  char* ws = (char*)d_ws;
  size_t off = 0;
  auto take = [&](size_t bytes) {
    char* p = ws + off;
    off = (off + bytes + 255) & ~(size_t)255;
    return p;
  };
  unsigned short* wcat2T = (unsigned short*)take((size_t)L_LAYERS * 128 * K_CAT * 2); // 0.8 MB
  unsigned short* xbf    = (unsigned short*)take((size_t)N_NODES * IN_C * 2);         // 25.6 MB
  unsigned short* w1T    = (unsigned short*)take((size_t)HID * IN_C * 2);             // 64 KB
  float* invc    = (float*)take((size_t)N_NODES * R_REL * 4);   // int cnt -> fp32 inv, in place
  int*   cntDst  = (int*)take((size_t)N_NODES * 4);
  int*   cursor  = (int*)take((size_t)N_NODES * 4);
  int*   tmpOff  = (int*)take((size_t)N_NODES * 4);
  int*   blockSums = (int*)take((size_t)SCAN_BLOCKS * 4);
  int*   dstStart  = (int*)take((size_t)(N_NODES + 1) * 4);
  int*   epack     = (int*)take((size_t)E_EDGES * 4);           // 2.4 MB
  float* hidden  = (float*)take((size_t)N_NODES * HID * 4);     // 25.6 MB
  unsigned short* curA = (unsigned short*)take((size_t)N_NODES * HID * 2); // 12.8 MB
  float* curB    = (float*)take((size_t)N_NODES * HID * 4);     // 25.6 MB
  unsigned short* aggB = (unsigned short*)take((size_t)N_NODES * AGG_COLS * 2); // 89.6 MB

  hipMemsetAsync(invc, 0, (size_t)N_NODES * R_REL * 4, stream);
  hipMemsetAsync(cntDst, 0, (size_t)N_NODES * 4, stream);
  hipMemsetAsync(cursor, 0, (size_t)N_NODES * 4, stream);

  hipLaunchKernelGGL(build_wcat2, dim3((L_LAYERS * 128 * K_CAT + 255) / 256),
                     dim3(256), 0, stream, comps, bases, roots, wcat2T);
  hipLaunchKernelGGL(cast_x_kernel, dim3((N_NODES * IN_C / 4 + 255) / 256),
                     dim3(256), 0, stream, x, xbf);
  hipLaunchKernelGGL(cast_w1_kernel, dim3((HID * IN_C + 255) / 256), dim3(256),
                     0, stream, w1, w1T);
  hipLaunchKernelGGL(hist_kernel, dim3((E_EDGES + 255) / 256), dim3(256), 0,
                     stream, ei, et, (int*)invc, cntDst);
  hipLaunchKernelGGL(inv_kernel, dim3((N_NODES * R_REL + 255) / 256), dim3(256),
                     0, stream, invc);
  hipLaunchKernelGGL(scan1_kernel, dim3(SCAN_BLOCKS), dim3(256), 0, stream,
                     cntDst, tmpOff, blockSums);
  hipLaunchKernelGGL(scan2_kernel, dim3(1), dim3(256), 0, stream, blockSums);
  hipLaunchKernelGGL(scan3_kernel, dim3(SCAN_BLOCKS), dim3(256), 0, stream,
                     tmpOff, blockSums, dstStart);
  hipLaunchKernelGGL(place_kernel, dim3((E_EDGES + 255) / 256), dim3(256), 0,
                     stream, ei, et, dstStart, cursor, epack);

  const int rowBlocks = (N_NODES + 127) / 128;   // 391
  hipLaunchKernelGGL(gemm_lin1, dim3(rowBlocks), dim3(256), 0, stream,
                     xbf, w1T, b1, temp, hidden, curA);

  for (int l = 0; l < L_LAYERS; ++l) {
    hipLaunchKernelGGL(agg2_kernel, dim3(N_NODES / 4), dim3(256), 0, stream,
                       curA, epack, dstStart, invc, aggB);
    hipLaunchKernelGGL(gemm_layer, dim3(rowBlocks), dim3(256), 0, stream,
                       curA, aggB, wcat2T + (size_t)l * 128 * K_CAT,
                       cbias + (size_t)l * HID, curB);
    hipLaunchKernelGGL(epilogue_kernel, dim3(N_NODES * HID / 4 / 256), dim3(256),
                       0, stream, curB, hidden, curA, temp, l);
  }

  hipLaunchKernelGGL(final_kernel, dim3((N_NODES + 3) / 4), dim3(256), 0, stream,
                     hidden, w2, b2, (float*)d_out);
}